// Round 8
// baseline (617.017 us; speedup 1.0000x reference)
//
#include <hip/hip_runtime.h>

// ============================================================================
// Persistent-kernel LSTM decoder, MI355X (gfx950) — round 14.
// r13 (464 µs decoder) = merged single-phase steps. r14 removes the last two
// serial latencies WITHOUT touching the proven stream structure:
//  1. BURST->EPILOGUE PRESTAGE: the first 5 ring sections of step t+1 are
//     staged during step t's epilogue, overlapping the pointwise/softmax:
//       G0: emb(t+1) — independent, no gate.
//       G1: h0(t+2) — G0 free-runs a full step ahead (nothing feeds back
//           into G0), so gate(SH0,t+2) in the epilogue resolves instantly;
//           prestage follows the gate (correct by construction).
//       logits: HS(t+1) after gate(SH1,t+2) in the epilogue.
//     At the next step top the binding gate fires into a resident ring.
//  2. G1 stream REORDERED h0-first / h1-second: the self-recurrence data
//     (h1(t-1)) is consumed in sections 8..15, staged from s=4 — detect+L
//     of the binding gate overlaps 8 sections of h0 compute. h0p pointwise
//     loads move to the step top (slot gated by the previous epilogue).
//  Wait-count schedules unchanged (prestage only turns waits into no-ops).
//  G1 accumulation order becomes h0-part-then-h1-part (ulp-level change).
// ============================================================================

typedef unsigned int uint;
typedef unsigned short ushort;
typedef unsigned long long u64;
typedef __attribute__((ext_vector_type(8))) __bf16 bf16x8;
typedef __attribute__((ext_vector_type(4))) float f32x4;
typedef __attribute__((ext_vector_type(8))) ushort ushort8v;

// ---- workspace byte offsets ----
#define OFF_CNT 0L
#define OFF_W0  4096L        // [32 ng][36 kc] B-frag, 2048x1152 bf16
#define OFF_W1  4722688L     // [32 ng][32 kc], 2048x1024
#define OFF_WO  8916992L     // [80 cg][20 kc], 5120x640 (vocab-padded)
#define OFF_EFT 15470592L    // [40 t][2 mt][16 kc] A-frag gathered emb
#define OFF_ZFT 25956352L    // [2 mt][4 kc] A-frag z
#define OFF_TW1 26021888L    // [64 ng][4 kc], 4096x128
#define OFF_TW2 27070464L    // [32 ng][64 kc], 2048x2048
#define OFF_GB  35459072L    // [2 l][2 mt][64 kc] A-frag relu hidden
#define OFF_C0  40701952L    // [256][512] f32
#define OFF_C1  41226240L    // [256][512] f32
#define OFF_MB  41750528L    // [4 slot][256][40] f32
#define OFF_SB  41914368L    // [4 slot][256][40] f32
#define OFF_TGT 42078208L    // [4 slot][256] f32
#define OFF_H0S 42205184L    // [40 slot][2 mt][16 kc] h0 sequence
#define OFF_H1S 52690944L    // [40 slot] h1 sequence
#define OFF_HSS 63176704L    // [39 slot] h0+h1 sequence

#define HPAR 262144L
#define HMT  131072L
#define SLOT_G 24576  // gate ring slot: A 16KB | B 8KB (ring of 5)
#define SLOT_L 32768  // logits ring slot: A 16KB | Blo 8KB | Bhi 8KB (ring of 4)

// signal word-indices within CNT:
//  SH0: 0   + mt*64 + g (g<32)   h0 step done -> value t+1
//  SH1: 128 + mt*64 + g (g<32)   h1+HS step done
//  SLG: 256 + mt*64 + g (g<40)   logits step done
//  SCB: 384 + mt*64 + g (g<16)   combine step done
//  SI1: 512 + p (p<128)          init1 done
//  SI2: 640 + p (p<64)           init2 done

// ---- relaxed agent-scope access helpers ----
__device__ __forceinline__ uint ald32(const uint* p) {
  return __hip_atomic_load(p, __ATOMIC_RELAXED, __HIP_MEMORY_SCOPE_AGENT);
}
__device__ __forceinline__ void ast32(uint* p, uint v) {
  __hip_atomic_store(p, v, __ATOMIC_RELAXED, __HIP_MEMORY_SCOPE_AGENT);
}
__device__ __forceinline__ float aldf(const float* p) {
  return __hip_atomic_load(p, __ATOMIC_RELAXED, __HIP_MEMORY_SCOPE_AGENT);
}
__device__ __forceinline__ void astf(float* p, float v) {
  __hip_atomic_store(p, v, __ATOMIC_RELAXED, __HIP_MEMORY_SCOPE_AGENT);
}
__device__ __forceinline__ void ast64(u64* p, u64 v) {
  __hip_atomic_store(p, v, __ATOMIC_RELAXED, __HIP_MEMORY_SCOPE_AGENT);
}

// producer post: drain all waves' stores, then ONE plain coherent store.
__device__ __forceinline__ void postS(uint* s, uint v) {
  __syncthreads();
  if (threadIdx.x == 0) ast32(s, v);
}

// consumer gate: wave0 polls n packed slots (lane li caches S[li]).
__device__ __forceinline__ void gateM(const uint* S, int n, u64 need, uint tgt, uint& vc) {
  if (threadIdx.x < 64) {
    const int li = threadIdx.x;
    uint v = (li < n) ? vc : 0xffffffffu;
    int r = 0;
    for (;;) {
      if ((__ballot((int)(v >= tgt)) & need) == need) break;
      if (li < n && v < tgt) v = ald32(S + li);
      if ((__ballot((int)(v >= tgt)) & need) == need) break;
      if (r < 2) __builtin_amdgcn_s_sleep(1);
      else if (r < 5) __builtin_amdgcn_s_sleep(4);
      else __builtin_amdgcn_s_sleep(8);
      ++r;
    }
    if (li < n) vc = v;
  }
  asm volatile("" ::: "memory");
  __builtin_amdgcn_s_barrier();
  asm volatile("" ::: "memory");
}

__device__ __forceinline__ ushort f2bf(float f) {
  uint u = __float_as_uint(f);
  u = (u + 0x7fffu + ((u >> 16) & 1u)) >> 16;  // RNE
  return (ushort)u;
}
__device__ __forceinline__ float bf2f(ushort u) { return __uint_as_float(((uint)u) << 16); }
__device__ __forceinline__ float sigm(float v) { return 1.f / (1.f + __expf(-v)); }
__device__ __forceinline__ float tanh_f(float v) {
  float a = fabsf(v);
  float e = __expf(-2.f * a);
  return copysignf((1.f - e) / (1.f + e), v);
}
__device__ __forceinline__ f32x4 mfma16(bf16x8 a, bf16x8 b, f32x4 c) {
  return __builtin_amdgcn_mfma_f32_16x16x32_bf16(a, b, c, 0, 0, 0);
}

__device__ __forceinline__ long fta(int b, int k, int KC) {
  return ((long)(((b >> 7) & 1) * KC + (k >> 5)) << 12) +
         (((((b >> 4) & 7) << 2) + ((k >> 3) & 3)) << 7) + ((b & 15) << 3) + (k & 7);
}

__device__ __forceinline__ void gl_lds16(const char* g, char* l) {
  __builtin_amdgcn_global_load_lds((const __attribute__((address_space(1))) void*)g,
                                   (__attribute__((address_space(3))) void*)l, 16, 0, 0);
}

__device__ __forceinline__ void stageA4(const char* A, char* dst, int o) {
#pragma unroll
  for (int i = 0; i < 4; ++i) gl_lds16(A + i * 4096 + o, dst + i * 4096 + o);
}
__device__ __forceinline__ void stage_gB(int bsec, const char* Bs, char* dst, int o) {
  const char* B = Bs + (long)bsec * 8192;
#pragma unroll
  for (int i = 0; i < 2; ++i) gl_lds16(B + i * 4096 + o, dst + 16384 + i * 4096 + o);
}
__device__ __forceinline__ void stage_lB(int bsec, const char* Blo, const char* Bhi, char* dst,
                                         int o) {
  const char* bl = Blo + (long)bsec * 8192;
  const char* bh = Bhi + (long)bsec * 8192;
#pragma unroll
  for (int i = 0; i < 2; ++i) gl_lds16(bl + i * 4096 + o, dst + 16384 + i * 4096 + o);
#pragma unroll
  for (int i = 0; i < 2; ++i) gl_lds16(bh + i * 4096 + o, dst + 24576 + i * 4096 + o);
}

// init-ring waits (6-load sections, all waves, ring of 5 / depth 4)
__device__ __forceinline__ void gw3(int r) {
  if (r <= 0) __builtin_amdgcn_s_waitcnt(0x0F70);       // vmcnt 0
  else if (r == 1) __builtin_amdgcn_s_waitcnt(0x0F76);  // 6
  else if (r == 2) __builtin_amdgcn_s_waitcnt(0x0F7C);  // 12
  else __builtin_amdgcn_s_waitcnt(0x4F72);              // 18
}
__device__ __forceinline__ void lw2(int r) {
  if (r <= 0) __builtin_amdgcn_s_waitcnt(0x0F70);       // 0
  else if (r == 1) __builtin_amdgcn_s_waitcnt(0x0F78);  // 8
  else __builtin_amdgcn_s_waitcnt(0x4F70);              // 16
}
// 16-section streamed phase (6 loads/thread/section; prestaged 5, trail 11)
__device__ __forceinline__ void gvw16(int s) {
  if (s == 0) __builtin_amdgcn_s_waitcnt(0x4F78);        // 24 (4 sections)
  else if (s <= 12) __builtin_amdgcn_s_waitcnt(0x4F72);  // 18 (3)
  else if (s == 13) __builtin_amdgcn_s_waitcnt(0x0F7C);  // 12 (2)
  else if (s == 14) __builtin_amdgcn_s_waitcnt(0x0F76);  // 6  (1)
  else __builtin_amdgcn_s_waitcnt(0x0F70);               // 0
}
// logits stream (8 loads/thread/section; prestaged 4, trail 4)
__device__ __forceinline__ void lvw8(int s) {
  if (s == 0) __builtin_amdgcn_s_waitcnt(0x4F78);       // 24 (3 sections)
  else if (s <= 5) __builtin_amdgcn_s_waitcnt(0x4F70);  // 16 (2)
  else if (s == 6) __builtin_amdgcn_s_waitcnt(0x0F78);  // 8  (1)
  else __builtin_amdgcn_s_waitcnt(0x0F70);              // 0
}

__device__ __forceinline__ void gemm_chunk_g(const char* sb, int ab, int bb, f32x4 (&acc)[4][2]) {
#pragma unroll
  for (int c = 0; c < 2; ++c) {
    const char* ap = sb + c * 8192 + ab;
    const char* bp = sb + c * 4096 + bb;
    bf16x8 Af0 = *(const bf16x8*)(ap);
    bf16x8 Af1 = *(const bf16x8*)(ap + 1024);
    bf16x8 Af2 = *(const bf16x8*)(ap + 2048);
    bf16x8 Af3 = *(const bf16x8*)(ap + 3072);
    bf16x8 Bf0 = *(const bf16x8*)(bp);
    bf16x8 Bf1 = *(const bf16x8*)(bp + 1024);
    acc[0][0] = mfma16(Af0, Bf0, acc[0][0]);
    acc[0][1] = mfma16(Af0, Bf1, acc[0][1]);
    acc[1][0] = mfma16(Af1, Bf0, acc[1][0]);
    acc[1][1] = mfma16(Af1, Bf1, acc[1][1]);
    acc[2][0] = mfma16(Af2, Bf0, acc[2][0]);
    acc[2][1] = mfma16(Af2, Bf1, acc[2][1]);
    acc[3][0] = mfma16(Af3, Bf0, acc[3][0]);
    acc[3][1] = mfma16(Af3, Bf1, acc[3][1]);
  }
}

__device__ __forceinline__ void gemm_chunk_l(const char* sb, int ab, int bb, f32x4 (&acc)[4][4]) {
#pragma unroll
  for (int c = 0; c < 2; ++c) {
    const char* ap = sb + c * 8192 + ab;
    const char* bp = sb + c * 4096 + bb;
    bf16x8 Af[4], Bf[4];
#pragma unroll
    for (int m = 0; m < 4; ++m) Af[m] = *(const bf16x8*)(ap + m * 1024);
#pragma unroll
    for (int n = 0; n < 4; ++n) Bf[n] = *(const bf16x8*)(bp + n * 1024);
#pragma unroll
    for (int m = 0; m < 4; ++m)
#pragma unroll
      for (int n = 0; n < 4; ++n) acc[m][n] = mfma16(Af[m], Bf[n], acc[m][n]);
  }
}

// ---- init-phase plain ring GEMM ----
__device__ __forceinline__ void run_gemm_init(const char* A0, const char* Bs, int S, char* smem,
                                              int tid, int wm, int wn, int lane,
                                              f32x4 (&acc)[4][2]) {
  const int o = tid * 16;
  const int D = S < 4 ? S : 4;
  for (int s = 0; s < D; ++s) {
    char* d = smem + s * SLOT_G;
    stageA4(A0 + (long)s * 16384, d, o);
    stage_gB(s, Bs, d, o);
  }
  const int ab = wm * 4096 + lane * 16;
  const int bb = 16384 + wn * 2048 + lane * 16;
  for (int s = 0; s < S; ++s) {
    const int rem = S - 1 - s;
    gw3(rem < 3 ? rem : 3);
    __builtin_amdgcn_s_barrier();
    char* sb = smem + (s % 5) * SLOT_G;
    if (s + 4 < S) {
      char* d = smem + ((s + 4) % 5) * SLOT_G;
      stageA4(A0 + (long)(s + 4) * 16384, d, o);
      stage_gB(s + 4, Bs, d, o);
    }
    gemm_chunk_g(sb, ab, bb, acc);
  }
  __syncthreads();
}

// C/D layout: col = lane&15, row = (lane>>4)*4 + reg
__device__ __forceinline__ void store_lds_tile(float* lds, f32x4 (&acc)[4][2], int wm, int wn,
                                               int lane) {
  const int l15 = lane & 15, lq = lane >> 4;
#pragma unroll
  for (int m = 0; m < 4; ++m)
#pragma unroll
    for (int n = 0; n < 2; ++n)
#pragma unroll
      for (int r = 0; r < 4; ++r)
        lds[(wm * 64 + m * 16 + lq * 4 + r) * 68 + (wn * 32 + n * 16 + l15)] = acc[m][n][r];
}
__device__ __forceinline__ void store_lds_tile128(float* lds, f32x4 (&acc)[4][4], int wm, int wn,
                                                  int lane) {
  const int l15 = lane & 15, lq = lane >> 4;
#pragma unroll
  for (int m = 0; m < 4; ++m)
#pragma unroll
    for (int n = 0; n < 4; ++n)
#pragma unroll
      for (int r = 0; r < 4; ++r)
        lds[(wm * 64 + m * 16 + lq * 4 + r) * 132 + (wn * 64 + n * 16 + l15)] = acc[m][n][r];
}

// LSTM gate pointwise; tile [128 b][16 d x 4 g] f32; C in registers.
template <bool WHS>
__device__ __forceinline__ void gates_pw4(const float* tile, int tid, int b0, int d0,
                                          const float* __restrict__ bg, float (&cp)[8],
                                          ushort* __restrict__ hw, const uint (&h0p)[4],
                                          ushort* __restrict__ hs) {
#pragma unroll
  for (int jj = 0; jj < 4; ++jj) {
    const int pi = tid + jj * 256;
    const int bl = pi >> 3, e = pi & 7;
    const f32x4 g0 = ((const f32x4*)tile)[bl * 17 + 2 * e];
    const f32x4 g1 = ((const f32x4*)tile)[bl * 17 + 2 * e + 1];
    const int d = d0 + 2 * e, b = b0 + bl;
    float h2[2];
#pragma unroll
    for (int u = 0; u < 2; ++u) {
      const f32x4 g = u ? g1 : g0;
      const int dd = d + u;
      const float ii = sigm(g[0] + bg[dd]);
      const float ff = sigm(g[1] + bg[512 + dd]);
      const float oo = sigm(g[2] + bg[1024 + dd]);
      const float cn = tanh_f(g[3] + bg[1536 + dd]);
      const float c = ff * cp[jj * 2 + u] + ii * cn;
      cp[jj * 2 + u] = c;
      h2[u] = oo * tanh_f(c);
    }
    const long ft = fta(b, d, 16);
    ast32((uint*)(hw + ft), (uint)f2bf(h2[0]) | ((uint)f2bf(h2[1]) << 16));
    if (WHS) {
      const uint h0v = h0p[jj];
      const float s0 = h2[0] + bf2f((ushort)(h0v & 0xffffu));
      const float s1 = h2[1] + bf2f((ushort)(h0v >> 16));
      ast32((uint*)(hs + ft), (uint)f2bf(s0) | ((uint)f2bf(s1) << 16));
    }
  }
}

__device__ __forceinline__ float combine_row4(const float* __restrict__ MBc,
                                              const float* __restrict__ SBc,
                                              const float* __restrict__ TGTc, int r, int lane) {
  float M = lane < 40 ? aldf(&MBc[r * 40 + lane]) : -3.0e38f;
  float S = lane < 40 ? aldf(&SBc[r * 40 + lane]) : 0.f;
#pragma unroll
  for (int off = 32; off > 0; off >>= 1) {
    const float Mo = __shfl_xor(M, off, 64);
    const float So = __shfl_xor(S, off, 64);
    const float Mn = fmaxf(M, Mo);
    S = S * __expf(M - Mn) + So * __expf(Mo - Mn);
    M = Mn;
  }
  return aldf(&TGTc[r]) - (M + __logf(S));
}

// ---------------------------------------------------------------------------
__device__ __forceinline__ void cv8(ushort8v& o, const float* s) {
  const f32x4 a = *(const f32x4*)s, b = *(const f32x4*)(s + 4);
#pragma unroll
  for (int j = 0; j < 4; ++j) o[j] = f2bf(a[j]);
#pragma unroll
  for (int j = 0; j < 4; ++j) o[4 + j] = f2bf(b[j]);
}
__device__ __forceinline__ void bft8(ushort* dst, int col, int kg, int KC, const float* src) {
  ushort8v o;
  cv8(o, src);
  *(ushort8v*)(dst + ((long)((col >> 6) * KC + (kg >> 2)) << 11) +
               (((((col >> 4) & 3) << 2) + (kg & 3)) << 7) + ((col & 15) << 3)) = o;
}
__device__ __forceinline__ void bft8z(ushort* dst, int col, int kg, int KC) {
  ushort8v o = (ushort8v)0;
  *(ushort8v*)(dst + ((long)((col >> 6) * KC + (kg >> 2)) << 11) +
               (((((col >> 4) & 3) << 2) + (kg & 3)) << 7) + ((col & 15) << 3)) = o;
}
__device__ __forceinline__ void aft8(ushort* dst, int b, int kg, int KC, const float* src) {
  ushort8v o;
  cv8(o, src);
  *(ushort8v*)(dst + ((long)(((b >> 7) & 1) * KC + (kg >> 2)) << 12) +
               (((((b >> 4) & 7) << 2) + (kg & 3)) << 7) + ((b & 15) << 3)) = o;
}

__global__ void __launch_bounds__(256) prep_kernel(
    const float* __restrict__ Wg0, const float* __restrict__ Wg1, const float* __restrict__ Wout,
    const float* __restrict__ emb, const float* __restrict__ z, const int* __restrict__ x,
    const float* __restrict__ tw1, const float* __restrict__ tw2, unsigned char* __restrict__ ws) {
  ushort* W0 = (ushort*)(ws + OFF_W0);
  ushort* W1 = (ushort*)(ws + OFF_W1);
  ushort* WO = (ushort*)(ws + OFF_WO);
  ushort* EF = (ushort*)(ws + OFF_EFT);
  ushort* ZF = (ushort*)(ws + OFF_ZFT);
  ushort* T1 = (ushort*)(ws + OFF_TW1);
  ushort* T2 = (ushort*)(ws + OFF_TW2);
  const long N0 = 294912, N1 = 262144, N2 = 409600, N3 = 655360, N4 = 4096, N5 = 65536,
             N6 = 524288;
  const long total = N0 + N1 + N2 + N3 + N4 + N5 + N6;
  for (long idx = (long)blockIdx.x * 256 + threadIdx.x; idx < total;
       idx += (long)gridDim.x * 256) {
    long j = idx;
    if (j < N0) {
      const int col = (int)(j / 144), kg = (int)(j - (long)col * 144);
      bft8(W0, col, kg, 36, Wg0 + (long)((col & 3) * 512 + (col >> 2)) * 1152 + kg * 8);
    } else if ((j -= N0) < N1) {
      const int col = (int)(j >> 7), kg = (int)(j & 127);
      bft8(W1, col, kg, 32, Wg1 + (long)((col & 3) * 512 + (col >> 2)) * 1024 + kg * 8);
    } else if ((j -= N1) < N2) {
      const int col = (int)(j / 80), kg = (int)(j - (long)col * 80);
      if (col < 5000)
        bft8(WO, col, kg, 20, Wout + (long)col * 640 + kg * 8);
      else
        bft8z(WO, col, kg, 20);
    } else if ((j -= N2) < N3) {
      const int t = (int)(j >> 14), r = (int)(j & 16383);
      const int b = r >> 6, kg = r & 63;
      aft8(EF + (long)t * 131072, b, kg, 16, emb + (long)x[b * 40 + t] * 512 + kg * 8);
    } else if ((j -= N3) < N4) {
      const int b = (int)(j >> 4), kg = (int)(j & 15);
      aft8(ZF, b, kg, 4, z + b * 128 + kg * 8);
    } else if ((j -= N4) < N5) {
      const int col = (int)(j >> 4), kg = (int)(j & 15);
      bft8(T1, col, kg, 4, tw1 + (long)(col >> 11) * 262144 + (long)(col & 2047) * 128 + kg * 8);
    } else {
      j -= N5;
      const int col = (int)(j >> 8), kg = (int)(j & 255);
      bft8(T2, col, kg, 64, tw2 + (long)(col >> 10) * 2097152 + (long)(col & 1023) * 2048 + kg * 8);
    }
  }
}

// ---------------------------------------------------------------------------
__global__ void __launch_bounds__(256) decoder_main(
    const int* __restrict__ x, const float* __restrict__ bg0, const float* __restrict__ bg1,
    const float* __restrict__ bout, const float* __restrict__ tb1, const float* __restrict__ tb2,
    unsigned char* __restrict__ ws, float* __restrict__ out) {
  __shared__ __align__(16) char smem[157696];  // 5*24576 ring + 34816 epi tile

  uint* CNT = (uint*)(ws + OFF_CNT);

  const char* cW0 = (const char*)(ws + OFF_W0);
  const char* cW1 = (const char*)(ws + OFF_W1);
  const char* cWO = (const char*)(ws + OFF_WO);
  const char* cEF = (const char*)(ws + OFF_EFT);
  const char* cZF = (const char*)(ws + OFF_ZFT);
  const char* cT1 = (const char*)(ws + OFF_TW1);
  const char* cT2 = (const char*)(ws + OFF_TW2);
  char* cGB = (char*)(ws + OFF_GB);
  char* cH0S = (char*)(ws + OFF_H0S);
  char* cH1S = (char*)(ws + OFF_H1S);
  char* cHSS = (char*)(ws + OFF_HSS);
  float* C0f = (float*)(ws + OFF_C0);
  float* C1f = (float*)(ws + OFF_C1);
  float* MBf = (float*)(ws + OFF_MB);
  float* SBf = (float*)(ws + OFF_SB);
  float* TGTf = (float*)(ws + OFF_TGT);

  const int bid = blockIdx.x;
  const int tid = threadIdx.x;
  const int lane = tid & 63;
  const int w = tid >> 6;
  const int wm = w & 1, wn = w >> 1;
  const int xcd = bid & 7;
  const int slot = bid >> 3;
  const int o16 = tid * 16;

  // ---- role map (XCD-affine; performance hint only) ----
  int role, mt_r = 0, idx = 0;
  if (xcd < 2) {
    role = 0; mt_r = xcd; idx = slot;          // G0
  } else if (xcd < 4) {
    role = 1; mt_r = xcd - 2; idx = slot;      // G1
  } else if (xcd < 6) {
    role = 2; mt_r = xcd - 4; idx = slot;      // logits lng 0..31
  } else if (slot < 8) {
    role = 2; mt_r = xcd - 6; idx = 32 + slot; // logits lng 32..39
  } else if (slot < 24) {
    role = 3; idx = (xcd - 6) * 16 + (slot - 8); mt_r = idx >> 4;  // combine
  } else {
    return;  // idle
  }

  const int ab = wm * 4096 + lane * 16;
  const int bbg = 16384 + wn * 2048 + lane * 16;
  const int bbl = 16384 + wn * 8192 + lane * 16;
  float* EPI = (float*)(smem + 122880);

  float cpriv[8];
  float accO0 = 0.f, accO1 = 0.f;

  // ======== init1 (128 blocks): relu(z @ tw1^T + tb1) -> GB ========
  if (bid < 128) {
    const int i_mt = bid & 1, i_ng = bid >> 1;
    f32x4 acc[4][2];
#pragma unroll
    for (int m = 0; m < 4; ++m)
#pragma unroll
      for (int n = 0; n < 2; ++n) acc[m][n] = (f32x4){0.f, 0.f, 0.f, 0.f};
    run_gemm_init(cZF + (long)i_mt * 32768, cT1 + (long)i_ng * 16384, 2, smem, tid, wm, wn,
                  lane, acc);
    store_lds_tile(EPI, acc, wm, wn, lane);
    __syncthreads();
    const int b0i = i_mt * 128, n0i = i_ng * 64;
    ushort* GBu = (ushort*)cGB;
    for (int i = tid; i < 2048; i += 256) {
      const int bl = i >> 4, q = i & 15;
      const f32x4 v = ((const f32x4*)EPI)[bl * 17 + q];
      const int cb = n0i + q * 4;
      const int l = cb >> 11, rr = cb & 2047;
      u64 pk = 0;
#pragma unroll
      for (int cc = 0; cc < 4; ++cc) pk |= (u64)f2bf(fmaxf(v[cc] + tb1[cb + cc], 0.f)) << (cc * 16);
      ast64((u64*)(GBu + (long)l * 524288 + fta(b0i + bl, rr, 64)), pk);
    }
    postS(CNT + 512 + bid, 1u);
  }

  // ======== init2 (64 blocks): tanh(GB @ tw2^T + tb2) -> (h seq 0, C) ========
  if (bid < 64) {
    uint ca = 0, cb2 = 0;
    gateM(CNT + 512, 64, ~0ull, 1u, ca);
    gateM(CNT + 576, 64, ~0ull, 1u, cb2);
    const int i_mt = bid & 1, i_ng = bid >> 1;
    const int l = i_ng >> 4;
    f32x4 acc[4][2];
#pragma unroll
    for (int m = 0; m < 4; ++m)
#pragma unroll
      for (int n = 0; n < 2; ++n) acc[m][n] = (f32x4){0.f, 0.f, 0.f, 0.f};
    run_gemm_init(cGB + (long)l * 1048576 + (long)i_mt * 524288, cT2 + (long)i_ng * 262144, 32,
                  smem, tid, wm, wn, lane, acc);
    store_lds_tile(EPI, acc, wm, wn, lane);
    __syncthreads();
    const int b0i = i_mt * 128, n0i = i_ng * 64;
    for (int i = tid; i < 2048; i += 256) {
      const int bl = i >> 4, q = i & 15;
      const f32x4 v = ((const f32x4*)EPI)[bl * 17 + q];
      const int cb = n0i + q * 4;
      const int ll = cb >> 10, rr = cb & 1023;
      const int b = b0i + bl;
      if (rr < 512) {
        u64 pk = 0;
#pragma unroll
        for (int cc = 0; cc < 4; ++cc) pk |= (u64)f2bf(tanh_f(v[cc] + tb2[cb + cc])) << (cc * 16);
        ast64((u64*)((ushort*)(ll ? cH1S : cH0S) + fta(b, rr, 16)), pk);
      } else {
        float* Cf = (ll ? C1f : C0f) + b * 512 + (rr - 512);
#pragma unroll
        for (int cc = 0; cc < 4; ++cc) astf(Cf + cc, tanh_f(v[cc] + tb2[cb + cc]));
      }
    }
    postS(CNT + 640 + bid, 1u);
  }

  // ======== role loops (39 steps) ========
  if (role == 0) {
    // ---- G0: emb prestaged in epilogue; h0(t-1) gated at top ----
    const int mt = mt_r, g = idx;
    uint* SH0m = CNT + mt * 64;
    const char* Az = cZF + (long)mt * 32768;
    const char* Bs = cW0 + (long)g * 147456;
    f32x4 pz0[4][2];
#pragma unroll
    for (int m = 0; m < 4; ++m)
#pragma unroll
      for (int n = 0; n < 2; ++n) pz0[m][n] = (f32x4){0.f, 0.f, 0.f, 0.f};
    run_gemm_init(Az, Bs + 131072, 2, smem, tid, wm, wn, lane, pz0);  // z-part (B 16..17)
    uint cI2 = 0, ch0 = 0;
    gateM(CNT + 640, 64, ~0ull, 1u, cI2);
#pragma unroll
    for (int jj = 0; jj < 4; ++jj) {
      const int pi = tid + jj * 256, bl = pi >> 3, e = pi & 7;
      cpriv[jj * 2 + 0] = aldf(&C0f[(mt * 128 + bl) * 512 + g * 16 + 2 * e]);
      cpriv[jj * 2 + 1] = aldf(&C0f[(mt * 128 + bl) * 512 + g * 16 + 2 * e + 1]);
    }
    uint dum[4] = {0, 0, 0, 0};
    // prologue: burst emb(0) secs 0..4 (B 8..12)
    {
      const char* Ae0 = cEF + (long)mt * HMT;
#pragma unroll
      for (int p = 0; p < 5; ++p) {
        char* d = smem + p * SLOT_G;
        stageA4(Ae0 + (long)p * 16384, d, o16);
        stage_gB(8 + p, Bs, d, o16);
      }
    }
    for (int t = 0; t < 39; ++t) {
      const char* Ae = cEF + (long)t * HPAR + (long)mt * HMT;
      const char* Ah = cH0S + (long)t * HPAR + (long)mt * HMT;  // h0(t-1)
      if (t >= 1) gateM(SH0m, 32, 0xFFFFFFFFull, (uint)t, ch0);
      f32x4 acc[4][2];
#pragma unroll
      for (int m = 0; m < 4; ++m)
#pragma unroll
        for (int n = 0; n < 2; ++n) acc[m][n] = pz0[m][n];
      // stream 16 sections: 0..7 emb (B 8..15, 0..4 prestaged), 8..15 h0 (B 0..7)
      for (int s = 0; s < 16; ++s) {
        gvw16(s);
        __builtin_amdgcn_s_barrier();
        const int sn = s + 4;
        if (s >= 1 && sn < 16) {
          char* d = smem + (sn % 5) * SLOT_G;
          if (sn < 8) {
            stageA4(Ae + (long)sn * 16384, d, o16);
            stage_gB(8 + sn, Bs, d, o16);
          } else {
            stageA4(Ah + (long)(sn - 8) * 16384, d, o16);
            stage_gB(sn - 8, Bs, d, o16);
          }
        }
        gemm_chunk_g(smem + (s % 5) * SLOT_G, ab, bbg, acc);
      }
      store_lds_tile(EPI, acc, wm, wn, lane);
      __syncthreads();
      // epilogue prestage: emb(t+1) secs 0..4 — L hides under pointwise
      if (t + 1 < 39) {
        const char* Aen = cEF + (long)(t + 1) * HPAR + (long)mt * HMT;
#pragma unroll
        for (int p = 0; p < 5; ++p) {
          char* d = smem + p * SLOT_G;
          stageA4(Aen + (long)p * 16384, d, o16);
          stage_gB(8 + p, Bs, d, o16);
        }
      }
      gates_pw4<false>(EPI, tid, mt * 128, g * 16, bg0, cpriv,
                       (ushort*)(cH0S + (long)(t + 1) * HPAR), dum, nullptr);
      postS(&SH0m[g], (uint)(t + 1));
    }
  } else if (role == 1) {
    // ---- G1 (+HS): h0-first stream; h0 prestaged in epilogue; h1 gated top ----
    const int mt = mt_r, g = idx;
    uint* SH0m = CNT + mt * 64;
    uint* SH1m = CNT + 128 + mt * 64;
    const char* Bs = cW1 + (long)g * 131072;
    uint cI2 = 0, ch1 = 0, ch0 = 0;
    gateM(CNT + 640, 64, ~0ull, 1u, cI2);
#pragma unroll
    for (int jj = 0; jj < 4; ++jj) {
      const int pi = tid + jj * 256, bl = pi >> 3, e = pi & 7;
      cpriv[jj * 2 + 0] = aldf(&C1f[(mt * 128 + bl) * 512 + g * 16 + 2 * e]);
      cpriv[jj * 2 + 1] = aldf(&C1f[(mt * 128 + bl) * 512 + g * 16 + 2 * e + 1]);
    }
    // prologue: gate h0 slot 1 then burst h0(slot1) secs 0..4 (B 8..12)
    gateM(SH0m, 32, 0xFFFFFFFFull, 1u, ch0);
    {
      const char* Ah0i = cH0S + 1L * HPAR + (long)mt * HMT;
#pragma unroll
      for (int p = 0; p < 5; ++p) {
        char* d = smem + p * SLOT_G;
        stageA4(Ah0i + (long)p * 16384, d, o16);
        stage_gB(8 + p, Bs, d, o16);
      }
    }
    for (int t = 0; t < 39; ++t) {
      const char* Ah0 = cH0S + (long)(t + 1) * HPAR + (long)mt * HMT;  // h0(t)
      const char* Ah1 = cH1S + (long)t * HPAR + (long)mt * HMT;        // h1(t-1)
      if (t >= 1) gateM(SH1m, 32, 0xFFFFFFFFull, (uint)t, ch1);  // binding self-gate
      // h0 pointwise operands at top (slot t+1 gated by previous epilogue)
      uint h0p[4];
      {
        const ushort* h0r = (const ushort*)(cH0S + (long)(t + 1) * HPAR);
#pragma unroll
        for (int jj = 0; jj < 4; ++jj) {
          const int pi = tid + jj * 256, bl = pi >> 3, e = pi & 7;
          h0p[jj] = *(const uint*)(h0r + fta(mt * 128 + bl, g * 16 + 2 * e, 16));
        }
      }
      f32x4 acc[4][2];
#pragma unroll
      for (int m = 0; m < 4; ++m)
#pragma unroll
        for (int n = 0; n < 2; ++n) acc[m][n] = (f32x4){0.f, 0.f, 0.f, 0.f};
      // stream 16: 0..7 h0(t) (B 8..15, 0..4 prestaged), 8..15 h1(t-1) (B 0..7)
      for (int s = 0; s < 16; ++s) {
        gvw16(s);
        __builtin_amdgcn_s_barrier();
        const int sn = s + 4;
        if (s >= 1 && sn < 16) {
          char* d = smem + (sn % 5) * SLOT_G;
          if (sn < 8) {
            stageA4(Ah0 + (long)sn * 16384, d, o16);
            stage_gB(8 + sn, Bs, d, o16);
          } else {
            stageA4(Ah1 + (long)(sn - 8) * 16384, d, o16);
            stage_gB(sn - 8, Bs, d, o16);
          }
        }
        gemm_chunk_g(smem + (s % 5) * SLOT_G, ab, bbg, acc);
      }
      store_lds_tile(EPI, acc, wm, wn, lane);
      __syncthreads();
      // epilogue: gate h0(t+2) (G0 runs ahead -> instant) + prestage h0 secs 0..4
      if (t + 1 < 39) {
        gateM(SH0m, 32, 0xFFFFFFFFull, (uint)(t + 2), ch0);
        const char* Ah0n = cH0S + (long)(t + 2) * HPAR + (long)mt * HMT;
#pragma unroll
        for (int p = 0; p < 5; ++p) {
          char* d = smem + p * SLOT_G;
          stageA4(Ah0n + (long)p * 16384, d, o16);
          stage_gB(8 + p, Bs, d, o16);
        }
      }
      gates_pw4<true>(EPI, tid, mt * 128, g * 16, bg1, cpriv,
                      (ushort*)(cH1S + (long)(t + 1) * HPAR), h0p,
                      (ushort*)(cHSS + (long)t * HPAR));
      postS(&SH1m[g], (uint)(t + 1));
    }
  } else if (role == 2) {
    // ---- logits: HS prestaged in epilogue ----
    const int lmt = mt_r, lng = idx;
    uint* SH1m = CNT + 128 + lmt * 64;
    uint* SLGm = CNT + 256 + lmt * 64;
    uint* SCBm = CNT + 384 + lmt * 64;
    const char* Blo = cWO + (long)(2 * lng) * 81920;
    const char* Bhi = cWO + (long)(2 * lng + 1) * 81920;
    const char* Az = cZF + (long)lmt * 32768;
    f32x4 pz[4][4];
#pragma unroll
    for (int m = 0; m < 4; ++m)
#pragma unroll
      for (int n = 0; n < 4; ++n) pz[m][n] = (f32x4){0.f, 0.f, 0.f, 0.f};
#pragma unroll
    for (int p = 0; p < 2; ++p) {
      char* d = smem + p * SLOT_L;
      stageA4(Az + (long)p * 16384, d, o16);
      stage_lB(8 + p, Blo, Bhi, d, o16);
    }
    for (int s = 0; s < 2; ++s) {
      lw2(1 - s);
      __builtin_amdgcn_s_barrier();
      gemm_chunk_l(smem + s * SLOT_L, ab, bbl, pz);
    }
    __syncthreads();
    {
      const int l15 = lane & 15;
#pragma unroll
      for (int n = 0; n < 4; ++n) {
        const int col = lng * 128 + wn * 64 + n * 16 + l15;
        const float bb = col < 5000 ? bout[col] : -3.0e38f;
#pragma unroll
        for (int m = 0; m < 4; ++m)
#pragma unroll
          for (int r = 0; r < 4; ++r) pz[m][n][r] += bb;
      }
    }
    uint ch1 = 0, ccb = 0;
    // prologue: gate HS(0) then burst secs 0..3
    gateM(SH1m, 32, 0xFFFFFFFFull, 1u, ch1);
    {
      const char* Ahs0 = cHSS + (long)lmt * HMT;
#pragma unroll
      for (int p = 0; p < 4; ++p) {
        char* d = smem + p * SLOT_L;
        stageA4(Ahs0 + (long)p * 16384, d, o16);
        stage_lB(p, Blo, Bhi, d, o16);
      }
    }
    for (int t = 0; t < 39; ++t) {
      const char* Ahs = cHSS + (long)t * HPAR + (long)lmt * HMT;
      if (t >= 4) gateM(SCBm, 16, 0xFFFFull, (uint)(t - 3), ccb);  // MB slot free
      gateM(SH1m, 32, 0xFFFFFFFFull, (uint)(t + 1), ch1);         // cached: no-op
      f32x4 acc[4][4];
#pragma unroll
      for (int m = 0; m < 4; ++m)
#pragma unroll
        for (int n = 0; n < 4; ++n) acc[m][n] = pz[m][n];
      // stream 8 sections (0..3 prestaged; trail 4..7)
      for (int s = 0; s < 8; ++s) {
        lvw8(s);
        __builtin_amdgcn_s_barrier();
        const int sn = s + 3;
        if (s >= 1 && sn < 8) {
          char* d = smem + (sn & 3) * SLOT_L;
          stageA4(Ahs + (long)sn * 16384, d, o16);
          stage_lB(sn, Blo, Bhi, d, o16);
        }
        gemm_chunk_l(smem + (s & 3) * SLOT_L, ab, bbl, acc);
      }
      __builtin_amdgcn_s_barrier();
      store_lds_tile128((float*)smem, acc, wm, wn, lane);
      __syncthreads();
      const int row = tid >> 1, half = tid & 1, b = lmt * 128 + row;
      const int n0 = lng * 128 + half * 64;
      const int xt = x[b * 40 + t + 1];
      const float* rowp = (const float*)smem + row * 132 + half * 64;
      float mx = -3.0e38f, tv = 0.f;
      for (int j = 0; j < 64; j += 4) {
        const f32x4 v = *(const f32x4*)(rowp + j);
#pragma unroll
        for (int cc = 0; cc < 4; ++cc) {
          mx = fmaxf(mx, v[cc]);
          if (n0 + j + cc == xt) tv = v[cc];
        }
      }
      float sa = 0.f;
      for (int j = 0; j < 64; j += 4) {
        const f32x4 v = *(const f32x4*)(rowp + j);
#pragma unroll
        for (int cc = 0; cc < 4; ++cc) sa += __expf(v[cc] - mx);
      }
      const float mo = __shfl_xor(mx, 1, 64), so = __shfl_xor(sa, 1, 64),
                  to = __shfl_xor(tv, 1, 64);
      const float Mn = fmaxf(mx, mo);
      const float Sm = sa * __expf(mx - Mn) + so * __expf(mo - Mn);
      const int sl = t & 3;
      if (half == 0) {
        astf(&MBf[sl * 10240 + b * 40 + lng], Mn);
        astf(&SBf[sl * 10240 + b * 40 + lng], Sm);
        if (xt >= lng * 128 && xt < lng * 128 + 128) astf(&TGTf[sl * 256 + b], tv + to);
      }
      __syncthreads();  // all softmax reads of the tile done before prestage
      // epilogue: gate HS(t+1) (G1 leads) + prestage secs 0..3
      if (t + 1 < 39) {
        gateM(SH1m, 32, 0xFFFFFFFFull, (uint)(t + 2), ch1);
        const char* Ahsn = cHSS + (long)(t + 1) * HPAR + (long)lmt * HMT;
#pragma unroll
        for (int p = 0; p < 4; ++p) {
          char* d = smem + p * SLOT_L;
          stageA4(Ahsn + (long)p * 16384, d, o16);
          stage_lB(p, Blo, Bhi, d, o16);
        }
      }
      postS(&SLGm[lng], (uint)(t + 1));
    }
  } else {
    // ---- combine (unchanged) ----
    const int cb = idx;
    const int cmt = mt_r;
    uint* SLGm = CNT + 256 + cmt * 64;
    uint* SCBm = CNT + 384 + cmt * 64;
    const int r0 = cb * 8 + w * 2;
    uint clg = 0;
    for (int t = 0; t < 39; ++t) {
      gateM(SLGm, 40, (1ull << 40) - 1, (uint)(t + 1), clg);
      const int sl = t & 3;
      accO0 += combine_row4(MBf + sl * 10240, SBf + sl * 10240, TGTf + sl * 256, r0, lane);
      accO1 += combine_row4(MBf + sl * 10240, SBf + sl * 10240, TGTf + sl * 256, r0 + 1, lane);
      postS(&SCBm[cb & 15], (uint)(t + 1));
    }
    if (lane == 0) {
      out[r0] = accO0;
      out[r0 + 1] = accO1;
    }
  }
}

// ---------------------------------------------------------------------------
extern "C" void kernel_launch(void* const* d_in, const int* in_sizes, int n_in, void* d_out,
                              int out_size, void* d_ws, size_t ws_size, hipStream_t stream) {
  const float* z = (const float*)d_in[0];
  const int* x = (const int*)d_in[1];
  const float* emb = (const float*)d_in[2];
  const float* Wg0 = (const float*)d_in[3];
  const float* bg0 = (const float*)d_in[4];
  const float* Wg1 = (const float*)d_in[5];
  const float* bg1 = (const float*)d_in[6];
  const float* Wout = (const float*)d_in[7];
  const float* bout = (const float*)d_in[8];
  const float* tw1 = (const float*)d_in[9];
  const float* tb1 = (const float*)d_in[10];
  const float* tw2 = (const float*)d_in[11];
  const float* tb2 = (const float*)d_in[12];
  unsigned char* ws = (unsigned char*)d_ws;
  float* out = (float*)d_out;

  hipMemsetAsync(ws, 0, 4096, stream);  // signal slots
  prep_kernel<<<2048, 256, 0, stream>>>(Wg0, Wg1, Wout, emb, z, x, tw1, tw2, ws);
  decoder_main<<<256, 256, 0, stream>>>(x, bg0, bg1, bout, tb1, tb2, ws, out);
}

// Round 9
// 549.937 us; speedup vs baseline: 1.1220x; 1.1220x over previous
//
#include <hip/hip_runtime.h>

// ============================================================================
// Persistent-kernel LSTM decoder, MI355X (gfx950) — round 15.
// r14's regression mechanism: postS() starts with __syncthreads(), whose
// implicit vmcnt(0) drained the epilogue-prestage loads (and r14 even put a
// blocking gate before postS) — every producer signal was delayed by ~L, and
// posts ARE the recurrence critical path. r15 = r13 skeleton with the
// epilogue prestage placed AFTER postS:
//  G0: post, then prestage emb(t+1) secs 0..4 (no gate). s=0 wait ~free.
//  G1: h0-FIRST stream (ulp-level reorder): h0(t) prestaged in epilogue
//      [postS -> gate SH0(t+2) -> prestage]; h1(t-1) (binding self-recurrence)
//      trail-staged after the top gate, consumed last -> burst-L leaves the
//      pacing cycle. h0p pointwise loads at step top (slot pre-gated).
//  logits: postS(SLG) -> gate SH1(t+2) -> prestage HS(t+1) secs 0..3.
// Wait ladders unchanged (prestage turns waits into no-ops; extra h0p loads
// only make them stricter). Combine/init identical to r13.
// ============================================================================

typedef unsigned int uint;
typedef unsigned short ushort;
typedef unsigned long long u64;
typedef __attribute__((ext_vector_type(8))) __bf16 bf16x8;
typedef __attribute__((ext_vector_type(4))) float f32x4;
typedef __attribute__((ext_vector_type(8))) ushort ushort8v;

// ---- workspace byte offsets ----
#define OFF_CNT 0L
#define OFF_W0  4096L        // [32 ng][36 kc] B-frag, 2048x1152 bf16
#define OFF_W1  4722688L     // [32 ng][32 kc], 2048x1024
#define OFF_WO  8916992L     // [80 cg][20 kc], 5120x640 (vocab-padded)
#define OFF_EFT 15470592L    // [40 t][2 mt][16 kc] A-frag gathered emb
#define OFF_ZFT 25956352L    // [2 mt][4 kc] A-frag z
#define OFF_TW1 26021888L    // [64 ng][4 kc], 4096x128
#define OFF_TW2 27070464L    // [32 ng][64 kc], 2048x2048
#define OFF_GB  35459072L    // [2 l][2 mt][64 kc] A-frag relu hidden
#define OFF_C0  40701952L    // [256][512] f32
#define OFF_C1  41226240L    // [256][512] f32
#define OFF_MB  41750528L    // [4 slot][256][40] f32
#define OFF_SB  41914368L    // [4 slot][256][40] f32
#define OFF_TGT 42078208L    // [4 slot][256] f32
#define OFF_H0S 42205184L    // [40 slot][2 mt][16 kc] h0 sequence
#define OFF_H1S 52690944L    // [40 slot] h1 sequence
#define OFF_HSS 63176704L    // [39 slot] h0+h1 sequence

#define HPAR 262144L
#define HMT  131072L
#define SLOT_G 24576  // gate ring slot: A 16KB | B 8KB (ring of 5)
#define SLOT_L 32768  // logits ring slot: A 16KB | Blo 8KB | Bhi 8KB (ring of 4)

// signal word-indices within CNT:
//  SH0: 0   + mt*64 + g (g<32)   h0 step done -> value t+1
//  SH1: 128 + mt*64 + g (g<32)   h1+HS step done
//  SLG: 256 + mt*64 + g (g<40)   logits step done
//  SCB: 384 + mt*64 + g (g<16)   combine step done
//  SI1: 512 + p (p<128)          init1 done
//  SI2: 640 + p (p<64)           init2 done

// ---- relaxed agent-scope access helpers ----
__device__ __forceinline__ uint ald32(const uint* p) {
  return __hip_atomic_load(p, __ATOMIC_RELAXED, __HIP_MEMORY_SCOPE_AGENT);
}
__device__ __forceinline__ void ast32(uint* p, uint v) {
  __hip_atomic_store(p, v, __ATOMIC_RELAXED, __HIP_MEMORY_SCOPE_AGENT);
}
__device__ __forceinline__ float aldf(const float* p) {
  return __hip_atomic_load(p, __ATOMIC_RELAXED, __HIP_MEMORY_SCOPE_AGENT);
}
__device__ __forceinline__ void astf(float* p, float v) {
  __hip_atomic_store(p, v, __ATOMIC_RELAXED, __HIP_MEMORY_SCOPE_AGENT);
}
__device__ __forceinline__ void ast64(u64* p, u64 v) {
  __hip_atomic_store(p, v, __ATOMIC_RELAXED, __HIP_MEMORY_SCOPE_AGENT);
}

// producer post: drain all waves' stores, then ONE plain coherent store.
// NOTHING with outstanding vmem may precede this in the epilogue.
__device__ __forceinline__ void postS(uint* s, uint v) {
  __syncthreads();
  if (threadIdx.x == 0) ast32(s, v);
}

// consumer gate: wave0 polls n packed slots (lane li caches S[li]).
__device__ __forceinline__ void gateM(const uint* S, int n, u64 need, uint tgt, uint& vc) {
  if (threadIdx.x < 64) {
    const int li = threadIdx.x;
    uint v = (li < n) ? vc : 0xffffffffu;
    int r = 0;
    for (;;) {
      if ((__ballot((int)(v >= tgt)) & need) == need) break;
      if (li < n && v < tgt) v = ald32(S + li);
      if ((__ballot((int)(v >= tgt)) & need) == need) break;
      if (r < 2) __builtin_amdgcn_s_sleep(1);
      else if (r < 5) __builtin_amdgcn_s_sleep(4);
      else __builtin_amdgcn_s_sleep(8);
      ++r;
    }
    if (li < n) vc = v;
  }
  asm volatile("" ::: "memory");
  __builtin_amdgcn_s_barrier();
  asm volatile("" ::: "memory");
}

__device__ __forceinline__ ushort f2bf(float f) {
  uint u = __float_as_uint(f);
  u = (u + 0x7fffu + ((u >> 16) & 1u)) >> 16;  // RNE
  return (ushort)u;
}
__device__ __forceinline__ float bf2f(ushort u) { return __uint_as_float(((uint)u) << 16); }
__device__ __forceinline__ float sigm(float v) { return 1.f / (1.f + __expf(-v)); }
__device__ __forceinline__ float tanh_f(float v) {
  float a = fabsf(v);
  float e = __expf(-2.f * a);
  return copysignf((1.f - e) / (1.f + e), v);
}
__device__ __forceinline__ f32x4 mfma16(bf16x8 a, bf16x8 b, f32x4 c) {
  return __builtin_amdgcn_mfma_f32_16x16x32_bf16(a, b, c, 0, 0, 0);
}

__device__ __forceinline__ long fta(int b, int k, int KC) {
  return ((long)(((b >> 7) & 1) * KC + (k >> 5)) << 12) +
         (((((b >> 4) & 7) << 2) + ((k >> 3) & 3)) << 7) + ((b & 15) << 3) + (k & 7);
}

__device__ __forceinline__ void gl_lds16(const char* g, char* l) {
  __builtin_amdgcn_global_load_lds((const __attribute__((address_space(1))) void*)g,
                                   (__attribute__((address_space(3))) void*)l, 16, 0, 0);
}

__device__ __forceinline__ void stageA4(const char* A, char* dst, int o) {
#pragma unroll
  for (int i = 0; i < 4; ++i) gl_lds16(A + i * 4096 + o, dst + i * 4096 + o);
}
__device__ __forceinline__ void stage_gB(int bsec, const char* Bs, char* dst, int o) {
  const char* B = Bs + (long)bsec * 8192;
#pragma unroll
  for (int i = 0; i < 2; ++i) gl_lds16(B + i * 4096 + o, dst + 16384 + i * 4096 + o);
}
__device__ __forceinline__ void stage_lB(int bsec, const char* Blo, const char* Bhi, char* dst,
                                         int o) {
  const char* bl = Blo + (long)bsec * 8192;
  const char* bh = Bhi + (long)bsec * 8192;
#pragma unroll
  for (int i = 0; i < 2; ++i) gl_lds16(bl + i * 4096 + o, dst + 16384 + i * 4096 + o);
#pragma unroll
  for (int i = 0; i < 2; ++i) gl_lds16(bh + i * 4096 + o, dst + 24576 + i * 4096 + o);
}

// init-ring waits (6-load sections, all waves, ring of 5 / depth 4)
__device__ __forceinline__ void gw3(int r) {
  if (r <= 0) __builtin_amdgcn_s_waitcnt(0x0F70);       // vmcnt 0
  else if (r == 1) __builtin_amdgcn_s_waitcnt(0x0F76);  // 6
  else if (r == 2) __builtin_amdgcn_s_waitcnt(0x0F7C);  // 12
  else __builtin_amdgcn_s_waitcnt(0x4F72);              // 18
}
__device__ __forceinline__ void lw2(int r) {
  if (r <= 0) __builtin_amdgcn_s_waitcnt(0x0F70);       // 0
  else if (r == 1) __builtin_amdgcn_s_waitcnt(0x0F78);  // 8
  else __builtin_amdgcn_s_waitcnt(0x4F70);              // 16
}
// 16-section streamed phase (6 loads/thread/section; prestaged 5, trail 11)
__device__ __forceinline__ void gvw16(int s) {
  if (s == 0) __builtin_amdgcn_s_waitcnt(0x4F78);        // 24 (4 sections)
  else if (s <= 12) __builtin_amdgcn_s_waitcnt(0x4F72);  // 18 (3)
  else if (s == 13) __builtin_amdgcn_s_waitcnt(0x0F7C);  // 12 (2)
  else if (s == 14) __builtin_amdgcn_s_waitcnt(0x0F76);  // 6  (1)
  else __builtin_amdgcn_s_waitcnt(0x0F70);               // 0
}
// logits stream (8 loads/thread/section; prestaged 4, trail 4)
__device__ __forceinline__ void lvw8(int s) {
  if (s == 0) __builtin_amdgcn_s_waitcnt(0x4F78);       // 24 (3 sections)
  else if (s <= 5) __builtin_amdgcn_s_waitcnt(0x4F70);  // 16 (2)
  else if (s == 6) __builtin_amdgcn_s_waitcnt(0x0F78);  // 8  (1)
  else __builtin_amdgcn_s_waitcnt(0x0F70);              // 0
}

__device__ __forceinline__ void gemm_chunk_g(const char* sb, int ab, int bb, f32x4 (&acc)[4][2]) {
#pragma unroll
  for (int c = 0; c < 2; ++c) {
    const char* ap = sb + c * 8192 + ab;
    const char* bp = sb + c * 4096 + bb;
    bf16x8 Af0 = *(const bf16x8*)(ap);
    bf16x8 Af1 = *(const bf16x8*)(ap + 1024);
    bf16x8 Af2 = *(const bf16x8*)(ap + 2048);
    bf16x8 Af3 = *(const bf16x8*)(ap + 3072);
    bf16x8 Bf0 = *(const bf16x8*)(bp);
    bf16x8 Bf1 = *(const bf16x8*)(bp + 1024);
    acc[0][0] = mfma16(Af0, Bf0, acc[0][0]);
    acc[0][1] = mfma16(Af0, Bf1, acc[0][1]);
    acc[1][0] = mfma16(Af1, Bf0, acc[1][0]);
    acc[1][1] = mfma16(Af1, Bf1, acc[1][1]);
    acc[2][0] = mfma16(Af2, Bf0, acc[2][0]);
    acc[2][1] = mfma16(Af2, Bf1, acc[2][1]);
    acc[3][0] = mfma16(Af3, Bf0, acc[3][0]);
    acc[3][1] = mfma16(Af3, Bf1, acc[3][1]);
  }
}

__device__ __forceinline__ void gemm_chunk_l(const char* sb, int ab, int bb, f32x4 (&acc)[4][4]) {
#pragma unroll
  for (int c = 0; c < 2; ++c) {
    const char* ap = sb + c * 8192 + ab;
    const char* bp = sb + c * 4096 + bb;
    bf16x8 Af[4], Bf[4];
#pragma unroll
    for (int m = 0; m < 4; ++m) Af[m] = *(const bf16x8*)(ap + m * 1024);
#pragma unroll
    for (int n = 0; n < 4; ++n) Bf[n] = *(const bf16x8*)(bp + n * 1024);
#pragma unroll
    for (int m = 0; m < 4; ++m)
#pragma unroll
      for (int n = 0; n < 4; ++n) acc[m][n] = mfma16(Af[m], Bf[n], acc[m][n]);
  }
}

// ---- init-phase plain ring GEMM ----
__device__ __forceinline__ void run_gemm_init(const char* A0, const char* Bs, int S, char* smem,
                                              int tid, int wm, int wn, int lane,
                                              f32x4 (&acc)[4][2]) {
  const int o = tid * 16;
  const int D = S < 4 ? S : 4;
  for (int s = 0; s < D; ++s) {
    char* d = smem + s * SLOT_G;
    stageA4(A0 + (long)s * 16384, d, o);
    stage_gB(s, Bs, d, o);
  }
  const int ab = wm * 4096 + lane * 16;
  const int bb = 16384 + wn * 2048 + lane * 16;
  for (int s = 0; s < S; ++s) {
    const int rem = S - 1 - s;
    gw3(rem < 3 ? rem : 3);
    __builtin_amdgcn_s_barrier();
    char* sb = smem + (s % 5) * SLOT_G;
    if (s + 4 < S) {
      char* d = smem + ((s + 4) % 5) * SLOT_G;
      stageA4(A0 + (long)(s + 4) * 16384, d, o);
      stage_gB(s + 4, Bs, d, o);
    }
    gemm_chunk_g(sb, ab, bb, acc);
  }
  __syncthreads();
}

// C/D layout: col = lane&15, row = (lane>>4)*4 + reg
__device__ __forceinline__ void store_lds_tile(float* lds, f32x4 (&acc)[4][2], int wm, int wn,
                                               int lane) {
  const int l15 = lane & 15, lq = lane >> 4;
#pragma unroll
  for (int m = 0; m < 4; ++m)
#pragma unroll
    for (int n = 0; n < 2; ++n)
#pragma unroll
      for (int r = 0; r < 4; ++r)
        lds[(wm * 64 + m * 16 + lq * 4 + r) * 68 + (wn * 32 + n * 16 + l15)] = acc[m][n][r];
}
__device__ __forceinline__ void store_lds_tile128(float* lds, f32x4 (&acc)[4][4], int wm, int wn,
                                                  int lane) {
  const int l15 = lane & 15, lq = lane >> 4;
#pragma unroll
  for (int m = 0; m < 4; ++m)
#pragma unroll
    for (int n = 0; n < 4; ++n)
#pragma unroll
      for (int r = 0; r < 4; ++r)
        lds[(wm * 64 + m * 16 + lq * 4 + r) * 132 + (wn * 64 + n * 16 + l15)] = acc[m][n][r];
}

// LSTM gate pointwise; tile [128 b][16 d x 4 g] f32; C in registers.
template <bool WHS>
__device__ __forceinline__ void gates_pw4(const float* tile, int tid, int b0, int d0,
                                          const float* __restrict__ bg, float (&cp)[8],
                                          ushort* __restrict__ hw, const uint (&h0p)[4],
                                          ushort* __restrict__ hs) {
#pragma unroll
  for (int jj = 0; jj < 4; ++jj) {
    const int pi = tid + jj * 256;
    const int bl = pi >> 3, e = pi & 7;
    const f32x4 g0 = ((const f32x4*)tile)[bl * 17 + 2 * e];
    const f32x4 g1 = ((const f32x4*)tile)[bl * 17 + 2 * e + 1];
    const int d = d0 + 2 * e, b = b0 + bl;
    float h2[2];
#pragma unroll
    for (int u = 0; u < 2; ++u) {
      const f32x4 g = u ? g1 : g0;
      const int dd = d + u;
      const float ii = sigm(g[0] + bg[dd]);
      const float ff = sigm(g[1] + bg[512 + dd]);
      const float oo = sigm(g[2] + bg[1024 + dd]);
      const float cn = tanh_f(g[3] + bg[1536 + dd]);
      const float c = ff * cp[jj * 2 + u] + ii * cn;
      cp[jj * 2 + u] = c;
      h2[u] = oo * tanh_f(c);
    }
    const long ft = fta(b, d, 16);
    ast32((uint*)(hw + ft), (uint)f2bf(h2[0]) | ((uint)f2bf(h2[1]) << 16));
    if (WHS) {
      const uint h0v = h0p[jj];
      const float s0 = h2[0] + bf2f((ushort)(h0v & 0xffffu));
      const float s1 = h2[1] + bf2f((ushort)(h0v >> 16));
      ast32((uint*)(hs + ft), (uint)f2bf(s0) | ((uint)f2bf(s1) << 16));
    }
  }
}

__device__ __forceinline__ float combine_row4(const float* __restrict__ MBc,
                                              const float* __restrict__ SBc,
                                              const float* __restrict__ TGTc, int r, int lane) {
  float M = lane < 40 ? aldf(&MBc[r * 40 + lane]) : -3.0e38f;
  float S = lane < 40 ? aldf(&SBc[r * 40 + lane]) : 0.f;
#pragma unroll
  for (int off = 32; off > 0; off >>= 1) {
    const float Mo = __shfl_xor(M, off, 64);
    const float So = __shfl_xor(S, off, 64);
    const float Mn = fmaxf(M, Mo);
    S = S * __expf(M - Mn) + So * __expf(Mo - Mn);
    M = Mn;
  }
  return aldf(&TGTc[r]) - (M + __logf(S));
}

// ---------------------------------------------------------------------------
__device__ __forceinline__ void cv8(ushort8v& o, const float* s) {
  const f32x4 a = *(const f32x4*)s, b = *(const f32x4*)(s + 4);
#pragma unroll
  for (int j = 0; j < 4; ++j) o[j] = f2bf(a[j]);
#pragma unroll
  for (int j = 0; j < 4; ++j) o[4 + j] = f2bf(b[j]);
}
__device__ __forceinline__ void bft8(ushort* dst, int col, int kg, int KC, const float* src) {
  ushort8v o;
  cv8(o, src);
  *(ushort8v*)(dst + ((long)((col >> 6) * KC + (kg >> 2)) << 11) +
               (((((col >> 4) & 3) << 2) + (kg & 3)) << 7) + ((col & 15) << 3)) = o;
}
__device__ __forceinline__ void bft8z(ushort* dst, int col, int kg, int KC) {
  ushort8v o = (ushort8v)0;
  *(ushort8v*)(dst + ((long)((col >> 6) * KC + (kg >> 2)) << 11) +
               (((((col >> 4) & 3) << 2) + (kg & 3)) << 7) + ((col & 15) << 3)) = o;
}
__device__ __forceinline__ void aft8(ushort* dst, int b, int kg, int KC, const float* src) {
  ushort8v o;
  cv8(o, src);
  *(ushort8v*)(dst + ((long)(((b >> 7) & 1) * KC + (kg >> 2)) << 12) +
               (((((b >> 4) & 7) << 2) + (kg & 3)) << 7) + ((b & 15) << 3)) = o;
}

__global__ void __launch_bounds__(256) prep_kernel(
    const float* __restrict__ Wg0, const float* __restrict__ Wg1, const float* __restrict__ Wout,
    const float* __restrict__ emb, const float* __restrict__ z, const int* __restrict__ x,
    const float* __restrict__ tw1, const float* __restrict__ tw2, unsigned char* __restrict__ ws) {
  ushort* W0 = (ushort*)(ws + OFF_W0);
  ushort* W1 = (ushort*)(ws + OFF_W1);
  ushort* WO = (ushort*)(ws + OFF_WO);
  ushort* EF = (ushort*)(ws + OFF_EFT);
  ushort* ZF = (ushort*)(ws + OFF_ZFT);
  ushort* T1 = (ushort*)(ws + OFF_TW1);
  ushort* T2 = (ushort*)(ws + OFF_TW2);
  const long N0 = 294912, N1 = 262144, N2 = 409600, N3 = 655360, N4 = 4096, N5 = 65536,
             N6 = 524288;
  const long total = N0 + N1 + N2 + N3 + N4 + N5 + N6;
  for (long idx = (long)blockIdx.x * 256 + threadIdx.x; idx < total;
       idx += (long)gridDim.x * 256) {
    long j = idx;
    if (j < N0) {
      const int col = (int)(j / 144), kg = (int)(j - (long)col * 144);
      bft8(W0, col, kg, 36, Wg0 + (long)((col & 3) * 512 + (col >> 2)) * 1152 + kg * 8);
    } else if ((j -= N0) < N1) {
      const int col = (int)(j >> 7), kg = (int)(j & 127);
      bft8(W1, col, kg, 32, Wg1 + (long)((col & 3) * 512 + (col >> 2)) * 1024 + kg * 8);
    } else if ((j -= N1) < N2) {
      const int col = (int)(j / 80), kg = (int)(j - (long)col * 80);
      if (col < 5000)
        bft8(WO, col, kg, 20, Wout + (long)col * 640 + kg * 8);
      else
        bft8z(WO, col, kg, 20);
    } else if ((j -= N2) < N3) {
      const int t = (int)(j >> 14), r = (int)(j & 16383);
      const int b = r >> 6, kg = r & 63;
      aft8(EF + (long)t * 131072, b, kg, 16, emb + (long)x[b * 40 + t] * 512 + kg * 8);
    } else if ((j -= N3) < N4) {
      const int b = (int)(j >> 4), kg = (int)(j & 15);
      aft8(ZF, b, kg, 4, z + b * 128 + kg * 8);
    } else if ((j -= N4) < N5) {
      const int col = (int)(j >> 4), kg = (int)(j & 15);
      bft8(T1, col, kg, 4, tw1 + (long)(col >> 11) * 262144 + (long)(col & 2047) * 128 + kg * 8);
    } else {
      j -= N5;
      const int col = (int)(j >> 8), kg = (int)(j & 255);
      bft8(T2, col, kg, 64, tw2 + (long)(col >> 10) * 2097152 + (long)(col & 1023) * 2048 + kg * 8);
    }
  }
}

// ---------------------------------------------------------------------------
__global__ void __launch_bounds__(256) decoder_main(
    const int* __restrict__ x, const float* __restrict__ bg0, const float* __restrict__ bg1,
    const float* __restrict__ bout, const float* __restrict__ tb1, const float* __restrict__ tb2,
    unsigned char* __restrict__ ws, float* __restrict__ out) {
  __shared__ __align__(16) char smem[157696];  // 5*24576 ring + 34816 epi tile

  uint* CNT = (uint*)(ws + OFF_CNT);

  const char* cW0 = (const char*)(ws + OFF_W0);
  const char* cW1 = (const char*)(ws + OFF_W1);
  const char* cWO = (const char*)(ws + OFF_WO);
  const char* cEF = (const char*)(ws + OFF_EFT);
  const char* cZF = (const char*)(ws + OFF_ZFT);
  const char* cT1 = (const char*)(ws + OFF_TW1);
  const char* cT2 = (const char*)(ws + OFF_TW2);
  char* cGB = (char*)(ws + OFF_GB);
  char* cH0S = (char*)(ws + OFF_H0S);
  char* cH1S = (char*)(ws + OFF_H1S);
  char* cHSS = (char*)(ws + OFF_HSS);
  float* C0f = (float*)(ws + OFF_C0);
  float* C1f = (float*)(ws + OFF_C1);
  float* MBf = (float*)(ws + OFF_MB);
  float* SBf = (float*)(ws + OFF_SB);
  float* TGTf = (float*)(ws + OFF_TGT);

  const int bid = blockIdx.x;
  const int tid = threadIdx.x;
  const int lane = tid & 63;
  const int w = tid >> 6;
  const int wm = w & 1, wn = w >> 1;
  const int xcd = bid & 7;
  const int slot = bid >> 3;
  const int o16 = tid * 16;

  // ---- role map (XCD-affine; performance hint only) ----
  int role, mt_r = 0, idx = 0;
  if (xcd < 2) {
    role = 0; mt_r = xcd; idx = slot;          // G0
  } else if (xcd < 4) {
    role = 1; mt_r = xcd - 2; idx = slot;      // G1
  } else if (xcd < 6) {
    role = 2; mt_r = xcd - 4; idx = slot;      // logits lng 0..31
  } else if (slot < 8) {
    role = 2; mt_r = xcd - 6; idx = 32 + slot; // logits lng 32..39
  } else if (slot < 24) {
    role = 3; idx = (xcd - 6) * 16 + (slot - 8); mt_r = idx >> 4;  // combine
  } else {
    return;  // idle
  }

  const int ab = wm * 4096 + lane * 16;
  const int bbg = 16384 + wn * 2048 + lane * 16;
  const int bbl = 16384 + wn * 8192 + lane * 16;
  float* EPI = (float*)(smem + 122880);

  float cpriv[8];
  float accO0 = 0.f, accO1 = 0.f;

  // ======== init1 (128 blocks): relu(z @ tw1^T + tb1) -> GB ========
  if (bid < 128) {
    const int i_mt = bid & 1, i_ng = bid >> 1;
    f32x4 acc[4][2];
#pragma unroll
    for (int m = 0; m < 4; ++m)
#pragma unroll
      for (int n = 0; n < 2; ++n) acc[m][n] = (f32x4){0.f, 0.f, 0.f, 0.f};
    run_gemm_init(cZF + (long)i_mt * 32768, cT1 + (long)i_ng * 16384, 2, smem, tid, wm, wn,
                  lane, acc);
    store_lds_tile(EPI, acc, wm, wn, lane);
    __syncthreads();
    const int b0i = i_mt * 128, n0i = i_ng * 64;
    ushort* GBu = (ushort*)cGB;
    for (int i = tid; i < 2048; i += 256) {
      const int bl = i >> 4, q = i & 15;
      const f32x4 v = ((const f32x4*)EPI)[bl * 17 + q];
      const int cb = n0i + q * 4;
      const int l = cb >> 11, rr = cb & 2047;
      u64 pk = 0;
#pragma unroll
      for (int cc = 0; cc < 4; ++cc) pk |= (u64)f2bf(fmaxf(v[cc] + tb1[cb + cc], 0.f)) << (cc * 16);
      ast64((u64*)(GBu + (long)l * 524288 + fta(b0i + bl, rr, 64)), pk);
    }
    postS(CNT + 512 + bid, 1u);
  }

  // ======== init2 (64 blocks): tanh(GB @ tw2^T + tb2) -> (h seq 0, C) ========
  if (bid < 64) {
    uint ca = 0, cb2 = 0;
    gateM(CNT + 512, 64, ~0ull, 1u, ca);
    gateM(CNT + 576, 64, ~0ull, 1u, cb2);
    const int i_mt = bid & 1, i_ng = bid >> 1;
    const int l = i_ng >> 4;
    f32x4 acc[4][2];
#pragma unroll
    for (int m = 0; m < 4; ++m)
#pragma unroll
      for (int n = 0; n < 2; ++n) acc[m][n] = (f32x4){0.f, 0.f, 0.f, 0.f};
    run_gemm_init(cGB + (long)l * 1048576 + (long)i_mt * 524288, cT2 + (long)i_ng * 262144, 32,
                  smem, tid, wm, wn, lane, acc);
    store_lds_tile(EPI, acc, wm, wn, lane);
    __syncthreads();
    const int b0i = i_mt * 128, n0i = i_ng * 64;
    for (int i = tid; i < 2048; i += 256) {
      const int bl = i >> 4, q = i & 15;
      const f32x4 v = ((const f32x4*)EPI)[bl * 17 + q];
      const int cb = n0i + q * 4;
      const int ll = cb >> 10, rr = cb & 1023;
      const int b = b0i + bl;
      if (rr < 512) {
        u64 pk = 0;
#pragma unroll
        for (int cc = 0; cc < 4; ++cc) pk |= (u64)f2bf(tanh_f(v[cc] + tb2[cb + cc])) << (cc * 16);
        ast64((u64*)((ushort*)(ll ? cH1S : cH0S) + fta(b, rr, 16)), pk);
      } else {
        float* Cf = (ll ? C1f : C0f) + b * 512 + (rr - 512);
#pragma unroll
        for (int cc = 0; cc < 4; ++cc) astf(Cf + cc, tanh_f(v[cc] + tb2[cb + cc]));
      }
    }
    postS(CNT + 640 + bid, 1u);
  }

  // ======== role loops (39 steps) ========
  if (role == 0) {
    // ---- G0: emb prestaged AFTER postS; h0(t-1) gated at top ----
    const int mt = mt_r, g = idx;
    uint* SH0m = CNT + mt * 64;
    const char* Az = cZF + (long)mt * 32768;
    const char* Bs = cW0 + (long)g * 147456;
    f32x4 pz0[4][2];
#pragma unroll
    for (int m = 0; m < 4; ++m)
#pragma unroll
      for (int n = 0; n < 2; ++n) pz0[m][n] = (f32x4){0.f, 0.f, 0.f, 0.f};
    run_gemm_init(Az, Bs + 131072, 2, smem, tid, wm, wn, lane, pz0);  // z-part (B 16..17)
    uint cI2 = 0, ch0 = 0;
    gateM(CNT + 640, 64, ~0ull, 1u, cI2);
#pragma unroll
    for (int jj = 0; jj < 4; ++jj) {
      const int pi = tid + jj * 256, bl = pi >> 3, e = pi & 7;
      cpriv[jj * 2 + 0] = aldf(&C0f[(mt * 128 + bl) * 512 + g * 16 + 2 * e]);
      cpriv[jj * 2 + 1] = aldf(&C0f[(mt * 128 + bl) * 512 + g * 16 + 2 * e + 1]);
    }
    uint dum[4] = {0, 0, 0, 0};
    // prologue: burst emb(0) secs 0..4 (B 8..12)
    {
      const char* Ae0 = cEF + (long)mt * HMT;
#pragma unroll
      for (int p = 0; p < 5; ++p) {
        char* d = smem + p * SLOT_G;
        stageA4(Ae0 + (long)p * 16384, d, o16);
        stage_gB(8 + p, Bs, d, o16);
      }
    }
    for (int t = 0; t < 39; ++t) {
      const char* Ae = cEF + (long)t * HPAR + (long)mt * HMT;
      const char* Ah = cH0S + (long)t * HPAR + (long)mt * HMT;  // h0(t-1)
      if (t >= 1) gateM(SH0m, 32, 0xFFFFFFFFull, (uint)t, ch0);
      f32x4 acc[4][2];
#pragma unroll
      for (int m = 0; m < 4; ++m)
#pragma unroll
        for (int n = 0; n < 2; ++n) acc[m][n] = pz0[m][n];
      // stream 16 sections: 0..7 emb (B 8..15, 0..4 prestaged), 8..15 h0 (B 0..7)
      for (int s = 0; s < 16; ++s) {
        gvw16(s);
        __builtin_amdgcn_s_barrier();
        const int sn = s + 4;
        if (s >= 1 && sn < 16) {
          char* d = smem + (sn % 5) * SLOT_G;
          if (sn < 8) {
            stageA4(Ae + (long)sn * 16384, d, o16);
            stage_gB(8 + sn, Bs, d, o16);
          } else {
            stageA4(Ah + (long)(sn - 8) * 16384, d, o16);
            stage_gB(sn - 8, Bs, d, o16);
          }
        }
        gemm_chunk_g(smem + (s % 5) * SLOT_G, ab, bbg, acc);
      }
      store_lds_tile(EPI, acc, wm, wn, lane);
      __syncthreads();
      gates_pw4<false>(EPI, tid, mt * 128, g * 16, bg0, cpriv,
                       (ushort*)(cH0S + (long)(t + 1) * HPAR), dum, nullptr);
      postS(&SH0m[g], (uint)(t + 1));
      // epilogue prestage AFTER post: emb(t+1) secs 0..4 (no gate needed)
      if (t + 1 < 39) {
        const char* Aen = cEF + (long)(t + 1) * HPAR + (long)mt * HMT;
#pragma unroll
        for (int p = 0; p < 5; ++p) {
          char* d = smem + p * SLOT_G;
          stageA4(Aen + (long)p * 16384, d, o16);
          stage_gB(8 + p, Bs, d, o16);
        }
      }
    }
  } else if (role == 1) {
    // ---- G1 (+HS): h0-first stream; h0 prestaged AFTER postS; h1 gated top ----
    const int mt = mt_r, g = idx;
    uint* SH0m = CNT + mt * 64;
    uint* SH1m = CNT + 128 + mt * 64;
    const char* Bs = cW1 + (long)g * 131072;
    uint cI2 = 0, ch1 = 0, ch0 = 0;
    gateM(CNT + 640, 64, ~0ull, 1u, cI2);
#pragma unroll
    for (int jj = 0; jj < 4; ++jj) {
      const int pi = tid + jj * 256, bl = pi >> 3, e = pi & 7;
      cpriv[jj * 2 + 0] = aldf(&C1f[(mt * 128 + bl) * 512 + g * 16 + 2 * e]);
      cpriv[jj * 2 + 1] = aldf(&C1f[(mt * 128 + bl) * 512 + g * 16 + 2 * e + 1]);
    }
    // prologue: gate h0 slot 1, burst h0(slot1) secs 0..4 (B 8..12)
    gateM(SH0m, 32, 0xFFFFFFFFull, 1u, ch0);
    {
      const char* Ah0i = cH0S + 1L * HPAR + (long)mt * HMT;
#pragma unroll
      for (int p = 0; p < 5; ++p) {
        char* d = smem + p * SLOT_G;
        stageA4(Ah0i + (long)p * 16384, d, o16);
        stage_gB(8 + p, Bs, d, o16);
      }
    }
    for (int t = 0; t < 39; ++t) {
      const char* Ah0 = cH0S + (long)(t + 1) * HPAR + (long)mt * HMT;  // h0(t)
      const char* Ah1 = cH1S + (long)t * HPAR + (long)mt * HMT;        // h1(t-1)
      if (t >= 1) gateM(SH1m, 32, 0xFFFFFFFFull, (uint)t, ch1);  // binding self-gate
      // h0 pointwise operands at top (slot t+1 gated by prologue/epilogue)
      uint h0p[4];
      {
        const ushort* h0r = (const ushort*)(cH0S + (long)(t + 1) * HPAR);
#pragma unroll
        for (int jj = 0; jj < 4; ++jj) {
          const int pi = tid + jj * 256, bl = pi >> 3, e = pi & 7;
          h0p[jj] = *(const uint*)(h0r + fta(mt * 128 + bl, g * 16 + 2 * e, 16));
        }
      }
      f32x4 acc[4][2];
#pragma unroll
      for (int m = 0; m < 4; ++m)
#pragma unroll
        for (int n = 0; n < 2; ++n) acc[m][n] = (f32x4){0.f, 0.f, 0.f, 0.f};
      // stream 16: 0..7 h0(t) (B 8..15, 0..4 prestaged), 8..15 h1(t-1) (B 0..7)
      for (int s = 0; s < 16; ++s) {
        gvw16(s);
        __builtin_amdgcn_s_barrier();
        const int sn = s + 4;
        if (s >= 1 && sn < 16) {
          char* d = smem + (sn % 5) * SLOT_G;
          if (sn < 8) {
            stageA4(Ah0 + (long)sn * 16384, d, o16);
            stage_gB(8 + sn, Bs, d, o16);
          } else {
            stageA4(Ah1 + (long)(sn - 8) * 16384, d, o16);
            stage_gB(sn - 8, Bs, d, o16);
          }
        }
        gemm_chunk_g(smem + (s % 5) * SLOT_G, ab, bbg, acc);
      }
      store_lds_tile(EPI, acc, wm, wn, lane);
      __syncthreads();
      gates_pw4<true>(EPI, tid, mt * 128, g * 16, bg1, cpriv,
                      (ushort*)(cH1S + (long)(t + 1) * HPAR), h0p,
                      (ushort*)(cHSS + (long)t * HPAR));
      postS(&SH1m[g], (uint)(t + 1));
      // epilogue AFTER post: gate h0(t+2) (G0 leads -> fast) + prestage secs 0..4
      if (t + 1 < 39) {
        gateM(SH0m, 32, 0xFFFFFFFFull, (uint)(t + 2), ch0);
        const char* Ah0n = cH0S + (long)(t + 2) * HPAR + (long)mt * HMT;
#pragma unroll
        for (int p = 0; p < 5; ++p) {
          char* d = smem + p * SLOT_G;
          stageA4(Ah0n + (long)p * 16384, d, o16);
          stage_gB(8 + p, Bs, d, o16);
        }
      }
    }
  } else if (role == 2) {
    // ---- logits: HS prestaged AFTER postS ----
    const int lmt = mt_r, lng = idx;
    uint* SH1m = CNT + 128 + lmt * 64;
    uint* SLGm = CNT + 256 + lmt * 64;
    uint* SCBm = CNT + 384 + lmt * 64;
    const char* Blo = cWO + (long)(2 * lng) * 81920;
    const char* Bhi = cWO + (long)(2 * lng + 1) * 81920;
    const char* Az = cZF + (long)lmt * 32768;
    f32x4 pz[4][4];
#pragma unroll
    for (int m = 0; m < 4; ++m)
#pragma unroll
      for (int n = 0; n < 4; ++n) pz[m][n] = (f32x4){0.f, 0.f, 0.f, 0.f};
#pragma unroll
    for (int p = 0; p < 2; ++p) {
      char* d = smem + p * SLOT_L;
      stageA4(Az + (long)p * 16384, d, o16);
      stage_lB(8 + p, Blo, Bhi, d, o16);
    }
    for (int s = 0; s < 2; ++s) {
      lw2(1 - s);
      __builtin_amdgcn_s_barrier();
      gemm_chunk_l(smem + s * SLOT_L, ab, bbl, pz);
    }
    __syncthreads();
    {
      const int l15 = lane & 15;
#pragma unroll
      for (int n = 0; n < 4; ++n) {
        const int col = lng * 128 + wn * 64 + n * 16 + l15;
        const float bb = col < 5000 ? bout[col] : -3.0e38f;
#pragma unroll
        for (int m = 0; m < 4; ++m)
#pragma unroll
          for (int r = 0; r < 4; ++r) pz[m][n][r] += bb;
      }
    }
    uint ch1 = 0, ccb = 0;
    // prologue: gate HS(0) then burst secs 0..3
    gateM(SH1m, 32, 0xFFFFFFFFull, 1u, ch1);
    {
      const char* Ahs0 = cHSS + (long)lmt * HMT;
#pragma unroll
      for (int p = 0; p < 4; ++p) {
        char* d = smem + p * SLOT_L;
        stageA4(Ahs0 + (long)p * 16384, d, o16);
        stage_lB(p, Blo, Bhi, d, o16);
      }
    }
    for (int t = 0; t < 39; ++t) {
      const char* Ahs = cHSS + (long)t * HPAR + (long)lmt * HMT;
      if (t >= 4) gateM(SCBm, 16, 0xFFFFull, (uint)(t - 3), ccb);  // MB slot free
      gateM(SH1m, 32, 0xFFFFFFFFull, (uint)(t + 1), ch1);          // cached: no-op
      f32x4 acc[4][4];
#pragma unroll
      for (int m = 0; m < 4; ++m)
#pragma unroll
        for (int n = 0; n < 4; ++n) acc[m][n] = pz[m][n];
      // stream 8 sections (0..3 prestaged; trail 4..7)
      for (int s = 0; s < 8; ++s) {
        lvw8(s);
        __builtin_amdgcn_s_barrier();
        const int sn = s + 3;
        if (s >= 1 && sn < 8) {
          char* d = smem + (sn & 3) * SLOT_L;
          stageA4(Ahs + (long)sn * 16384, d, o16);
          stage_lB(sn, Blo, Bhi, d, o16);
        }
        gemm_chunk_l(smem + (s & 3) * SLOT_L, ab, bbl, acc);
      }
      __builtin_amdgcn_s_barrier();
      store_lds_tile128((float*)smem, acc, wm, wn, lane);
      __syncthreads();
      const int row = tid >> 1, half = tid & 1, b = lmt * 128 + row;
      const int n0 = lng * 128 + half * 64;
      const int xt = x[b * 40 + t + 1];
      const float* rowp = (const float*)smem + row * 132 + half * 64;
      float mx = -3.0e38f, tv = 0.f;
      for (int j = 0; j < 64; j += 4) {
        const f32x4 v = *(const f32x4*)(rowp + j);
#pragma unroll
        for (int cc = 0; cc < 4; ++cc) {
          mx = fmaxf(mx, v[cc]);
          if (n0 + j + cc == xt) tv = v[cc];
        }
      }
      float sa = 0.f;
      for (int j = 0; j < 64; j += 4) {
        const f32x4 v = *(const f32x4*)(rowp + j);
#pragma unroll
        for (int cc = 0; cc < 4; ++cc) sa += __expf(v[cc] - mx);
      }
      const float mo = __shfl_xor(mx, 1, 64), so = __shfl_xor(sa, 1, 64),
                  to = __shfl_xor(tv, 1, 64);
      const float Mn = fmaxf(mx, mo);
      const float Sm = sa * __expf(mx - Mn) + so * __expf(mo - Mn);
      const int sl = t & 3;
      if (half == 0) {
        astf(&MBf[sl * 10240 + b * 40 + lng], Mn);
        astf(&SBf[sl * 10240 + b * 40 + lng], Sm);
        if (xt >= lng * 128 && xt < lng * 128 + 128) astf(&TGTf[sl * 256 + b], tv + to);
      }
      postS(&SLGm[lng], (uint)(t + 1));
      // epilogue AFTER post: gate HS(t+1) ready (SH1 >= t+2) + prestage secs 0..3
      if (t + 1 < 39) {
        gateM(SH1m, 32, 0xFFFFFFFFull, (uint)(t + 2), ch1);
        const char* Ahsn = cHSS + (long)(t + 1) * HPAR + (long)lmt * HMT;
#pragma unroll
        for (int p = 0; p < 4; ++p) {
          char* d = smem + p * SLOT_L;
          stageA4(Ahsn + (long)p * 16384, d, o16);
          stage_lB(p, Blo, Bhi, d, o16);
        }
      }
    }
  } else {
    // ---- combine (unchanged) ----
    const int cb = idx;
    const int cmt = mt_r;
    uint* SLGm = CNT + 256 + cmt * 64;
    uint* SCBm = CNT + 384 + cmt * 64;
    const int r0 = cb * 8 + w * 2;
    uint clg = 0;
    for (int t = 0; t < 39; ++t) {
      gateM(SLGm, 40, (1ull << 40) - 1, (uint)(t + 1), clg);
      const int sl = t & 3;
      accO0 += combine_row4(MBf + sl * 10240, SBf + sl * 10240, TGTf + sl * 256, r0, lane);
      accO1 += combine_row4(MBf + sl * 10240, SBf + sl * 10240, TGTf + sl * 256, r0 + 1, lane);
      postS(&SCBm[cb & 15], (uint)(t + 1));
    }
    if (lane == 0) {
      out[r0] = accO0;
      out[r0 + 1] = accO1;
    }
  }
}

// ---------------------------------------------------------------------------
extern "C" void kernel_launch(void* const* d_in, const int* in_sizes, int n_in, void* d_out,
                              int out_size, void* d_ws, size_t ws_size, hipStream_t stream) {
  const float* z = (const float*)d_in[0];
  const int* x = (const int*)d_in[1];
  const float* emb = (const float*)d_in[2];
  const float* Wg0 = (const float*)d_in[3];
  const float* bg0 = (const float*)d_in[4];
  const float* Wg1 = (const float*)d_in[5];
  const float* bg1 = (const float*)d_in[6];
  const float* Wout = (const float*)d_in[7];
  const float* bout = (const float*)d_in[8];
  const float* tw1 = (const float*)d_in[9];
  const float* tb1 = (const float*)d_in[10];
  const float* tw2 = (const float*)d_in[11];
  const float* tb2 = (const float*)d_in[12];
  unsigned char* ws = (unsigned char*)d_ws;
  float* out = (float*)d_out;

  hipMemsetAsync(ws, 0, 4096, stream);  // signal slots
  prep_kernel<<<2048, 256, 0, stream>>>(Wg0, Wg1, Wout, emb, z, x, tw1, tw2, ws);
  decoder_main<<<256, 256, 0, stream>>>(x, bg0, bg1, bout, tb1, tb2, ws, out);
}